// Round 3
// baseline (177.158 us; speedup 1.0000x reference)
//
#include <hip/hip_runtime.h>

// LFR frame stacking: x (B=64, T=4096, D=80) f32, lens (B,) i32
// out (B, NF=683, M*D=560) f32 ++ new_len (B,) f32
//
// Derived semantics (verified, absmax 0.0): T_all_max = 4099 fixed (lens[0]=T),
// NF = (4099-7)/6+1 = 683. Gather index for output position t=6f+m:
//   src = 0 if t<3; t-3 if t<3+lens[b]; else T-1.
//
// Round 3 (final consolidation): timed dur_us = 2x harness fill (~115-122us,
// untouchable, +-7us run noise) + kernel (~34us inferred vs ~23us floor on
// 140 MB mandatory traffic). Changes: (a) lens staged in LDS once per block
// (removes 6.1M global dword loads from the load-address critical path);
// (b) 8-way unroll, all loads issued before any store (8x16B MLP/thread);
// (c) NT stores kept. If this lands within fill noise, kernel is at its
// measurable limit -> roofline.

typedef float __attribute__((ext_vector_type(4))) f32x4;

constexpr int B    = 64;
constexpr int T    = 4096;
constexpr int D    = 80;
constexpr int NF   = 683;
constexpr int M    = 7;
constexpr int N    = 6;
constexpr int LEFT = 3;

constexpr int D4     = D / 4;         // 20 float4 per frame
constexpr int ROW4   = M * D4;        // 140 float4 per output row
constexpr int TOTAL4 = B * NF * ROW4; // 6,119,680 float4 total
constexpr int UNROLL = 8;

__device__ __forceinline__ int src_index(int idx, const int* __restrict__ s_lens) {
    int row = idx / ROW4;          // (b, f) flat
    int r   = idx - row * ROW4;    // position within row, [0,140)
    int b   = row / NF;
    int f   = row - b * NF;
    int m   = r / D4;              // which of M frames
    int d4  = r - m * D4;          // float4 within frame
    int t   = f * N + m;           // gather position in padded time axis
    int L   = s_lens[b];           // LDS broadcast, off the global path
    int src = (t < LEFT) ? 0 : (t < LEFT + L) ? (t - LEFT) : (T - 1);
    return (b * T + src) * D4 + d4;
}

__global__ __launch_bounds__(256) void lfr_kernel(
    const f32x4* __restrict__ x,      // (B*T*D4) float4
    const int*   __restrict__ lens,   // (B,)
    f32x4*       __restrict__ out,    // (B*NF*ROW4) float4
    float*       __restrict__ new_len) // (B,)
{
    __shared__ int s_lens[B];
    if (threadIdx.x < B) s_lens[threadIdx.x] = lens[threadIdx.x];
    __syncthreads();

    // fused tiny output: new_len
    if (blockIdx.x == 0 && threadIdx.x < B) {
        int L   = s_lens[threadIdx.x];
        int rem = L % N;
        int rp  = (rem == 1) ? 3 : (rem == 2) ? 2 : (rem == 3) ? 1 : 0;
        new_len[threadIdx.x] = (float)((LEFT + L + rp) / N);
    }

    int base = blockIdx.x * (256 * UNROLL) + (int)threadIdx.x;

    int   idx[UNROLL];
    bool  ok[UNROLL];
    f32x4 v[UNROLL];

    #pragma unroll
    for (int u = 0; u < UNROLL; ++u) {
        idx[u] = base + u * 256;
        ok[u]  = idx[u] < TOTAL4;
    }

    // Issue all loads before any store — UNROLL x 16B outstanding per thread.
    #pragma unroll
    for (int u = 0; u < UNROLL; ++u)
        if (ok[u]) v[u] = x[src_index(idx[u], s_lens)];

    #pragma unroll
    for (int u = 0; u < UNROLL; ++u)
        if (ok[u]) __builtin_nontemporal_store(v[u], &out[idx[u]]);
}

extern "C" void kernel_launch(void* const* d_in, const int* in_sizes, int n_in,
                              void* d_out, int out_size, void* d_ws, size_t ws_size,
                              hipStream_t stream) {
    const f32x4* x    = (const f32x4*)d_in[0];
    const int*   lens = (const int*)d_in[1];
    float*       out  = (float*)d_out;
    float*       nl   = out + (size_t)B * NF * M * D; // new_len after main output

    int blocks = (TOTAL4 + 256 * UNROLL - 1) / (256 * UNROLL); // 2989
    lfr_kernel<<<blocks, 256, 0, stream>>>(x, lens, (f32x4*)out, nl);
}

// Round 4
// 153.671 us; speedup vs baseline: 1.1528x; 1.1528x over previous
//
#include <hip/hip_runtime.h>

// LFR frame stacking: x (B=64, T=4096, D=80) f32, lens (B,) i32
// out (B, NF=683, M*D=560) f32 ++ new_len (B,) f32
//
// Derived semantics (verified, absmax 0.0): T_all_max = 4099 fixed (lens[0]=T),
// NF = (4099-7)/6+1 = 683. Gather index for output position t=6f+m:
//   src = 0 if t<3; t-3 if t<3+lens[b]; else T-1.
//
// Round 4: REVERT R3's 8-way+LDS regression (59.5us measured, latency-bound,
// VALUBusy 23.6%). Back to 2 elem/thread + NT stores (R1-family, ~32us
// clock-normalized). New lever: paired mapping gid and gid+TOTAL4/2 —
// since TOTAL4/2 = 21856 rows exactly, the pair shares (row%, f, m, d4, t):
// the full division chain (/140, /683, /20) runs ONCE per pair; elem 2 costs
// only lens[b+32] + 1 cmp/cndmask + const offset. Both streams lane-dense.
// R3 counters: FETCH only 19.3 MB (x is L3-resident) + WRITE 95.6 MB ->
// HBM floor ~18-19us; fills (2x ~58us, +-7us noise) dominate the timed total.

typedef float __attribute__((ext_vector_type(4))) f32x4;

constexpr int B    = 64;
constexpr int T    = 4096;
constexpr int D    = 80;
constexpr int NF   = 683;
constexpr int M    = 7;
constexpr int N    = 6;
constexpr int LEFT = 3;

constexpr int D4     = D / 4;          // 20 float4 per frame
constexpr int ROW4   = M * D4;         // 140 float4 per output row
constexpr int TOTAL4 = B * NF * ROW4;  // 6,119,680 float4 total
constexpr int HALF4  = TOTAL4 / 2;     // 3,059,840 = 21,856 rows * ROW4
constexpr int HALF_B = B / 2;          // batch offset between pair elements: 32

__global__ __launch_bounds__(256) void lfr_kernel(
    const f32x4* __restrict__ x,       // (B*T*D4) float4
    const int*   __restrict__ lens,    // (B,)
    f32x4*       __restrict__ out,     // (B*NF*ROW4) float4
    float*       __restrict__ new_len) // (B,)
{
    // fused tiny output: new_len
    if (blockIdx.x == 0 && threadIdx.x < B) {
        int L   = lens[threadIdx.x];
        int rem = L % N;
        int rp  = (rem == 1) ? 3 : (rem == 2) ? 2 : (rem == 3) ? 1 : 0;
        new_len[threadIdx.x] = (float)((LEFT + L + rp) / N);
    }

    int gid = blockIdx.x * 256 + (int)threadIdx.x;
    if (gid >= HALF4) return;

    // Shared index math for the pair (gid, gid + HALF4).
    int row = gid / ROW4;           // (b, f) flat, b in [0,32)
    int r   = gid - row * ROW4;     // [0,140)
    int b   = row / NF;
    int f   = row - b * NF;
    int m   = r / D4;
    int d4  = r - m * D4;
    int t   = f * N + m;            // same t for both elements

    int L0 = lens[b];
    int L1 = lens[b + HALF_B];

    int base = t - LEFT;
    int src0 = (t < LEFT) ? 0 : (t < LEFT + L0) ? base : (T - 1);
    int src1 = (t < LEFT) ? 0 : (t < LEFT + L1) ? base : (T - 1);

    int a0 = (b * T + src0) * D4 + d4;
    int a1 = ((b + HALF_B) * T + src1) * D4 + d4;

    // Both loads in flight before either store.
    f32x4 v0 = x[a0];
    f32x4 v1 = x[a1];

    __builtin_nontemporal_store(v0, &out[gid]);
    __builtin_nontemporal_store(v1, &out[gid + HALF4]);
}

extern "C" void kernel_launch(void* const* d_in, const int* in_sizes, int n_in,
                              void* d_out, int out_size, void* d_ws, size_t ws_size,
                              hipStream_t stream) {
    const f32x4* x    = (const f32x4*)d_in[0];
    const int*   lens = (const int*)d_in[1];
    float*       out  = (float*)d_out;
    float*       nl   = out + (size_t)B * NF * M * D; // new_len after main output

    int blocks = (HALF4 + 255) / 256; // 11,953
    lfr_kernel<<<blocks, 256, 0, stream>>>(x, lens, (f32x4*)out, nl);
}